// Round 3
// 370.085 us; speedup vs baseline: 1.0148x; 1.0148x over previous
//
#include <hip/hip_runtime.h>

#define N_TOK  1024
#define D_DIM  1024
#define M_FFN  4096

typedef float f32x4 __attribute__((ext_vector_type(4)));

__device__ __forceinline__ float wave_reduce(float v) {
    #pragma unroll
    for (int off = 32; off > 0; off >>= 1) v += __shfl_xor(v, off);
    return v;
}

// ---------------- LayerNorm over 1024-elem rows, f32 -> f32 ---------------
__global__ void ln_kernel(const float* __restrict__ X,
                          const float* __restrict__ gam,
                          const float* __restrict__ bet,
                          float* __restrict__ Y) {
    int b = blockIdx.x, t = threadIdx.x;           // 256 threads, 4 elems each
    float4 x = ((const float4*)(X + (size_t)b * N_TOK))[t];
    float s = x.x + x.y + x.z + x.w;
    float q = x.x*x.x + x.y*x.y + x.z*x.z + x.w*x.w;
    s = wave_reduce(s); q = wave_reduce(q);
    __shared__ float sa[4], sb[4];
    int wid = t >> 6;
    if ((t & 63) == 0) { sa[wid] = s; sb[wid] = q; }
    __syncthreads();
    float ts = sa[0] + sa[1] + sa[2] + sa[3];
    float tq = sb[0] + sb[1] + sb[2] + sb[3];
    float mean = ts * (1.f / N_TOK);
    float var  = tq * (1.f / N_TOK) - mean * mean;
    float rs = rsqrtf(var + 1e-5f);
    float4 g4 = ((const float4*)gam)[t];
    float4 b4 = ((const float4*)bet)[t];
    float4 o;
    o.x = (x.x - mean) * rs * g4.x + b4.x;
    o.y = (x.y - mean) * rs * g4.y + b4.y;
    o.z = (x.z - mean) * rs * g4.z + b4.z;
    o.w = (x.w - mean) * rs * g4.w + b4.w;
    ((float4*)(Y + (size_t)b * N_TOK))[t] = o;
}

// ---- C(32 x N) = A(32 x K) @ W(N x K)^T, lanes span K (coalesced W) ------
// R5-form inner loop. mode 0: plain store (split-K slabs), mode 1: bias+silu.
// No atomics anywhere -> no zero-init dependency -> no memset node.
__device__ __forceinline__ void gemm_body(const float* __restrict__ A,
                                          const float* __restrict__ W,
                                          float* __restrict__ C,
                                          const float* __restrict__ bias,
                                          int N, int K, int kchunk, int mode,
                                          int bx, int by) {
    int t = threadIdx.x;
    int lane = t & 63, wid = t >> 6;
    int ksub = lane & 15, nsub = lane >> 4;
    int mhalf = wid & 1, ngrp = wid >> 1;
    int n = bx * 8 + ngrp * 4 + nsub;
    int k0 = by * kchunk + ksub * 4;
    const float* wp = W + (size_t)n * K + k0;
    const float* ap = A + (size_t)mhalf * 16 * K + k0;
    float acc[16];
    #pragma unroll
    for (int j = 0; j < 16; j++) acc[j] = 0.f;
    for (int kk = 0; kk < kchunk; kk += 64) {
        f32x4 w4 = __builtin_nontemporal_load((const f32x4*)(wp + kk));
        #pragma unroll
        for (int j = 0; j < 16; j++) {
            float4 a4 = *(const float4*)(ap + (size_t)j * K + kk);
            acc[j] += a4.x*w4.x + a4.y*w4.y + a4.z*w4.z + a4.w*w4.w;
        }
    }
    #pragma unroll
    for (int j = 0; j < 16; j++) {
        #pragma unroll
        for (int off = 1; off < 16; off <<= 1)
            acc[j] += __shfl_xor(acc[j], off);
    }
    if (ksub == 0) {
        int mbase = mhalf * 16;
        if (mode == 1) {
            float bn = bias[n];
            #pragma unroll
            for (int j = 0; j < 16; j++) {
                float z = acc[j] + bn;
                C[(size_t)(mbase + j) * N + n] = z / (1.f + __expf(-z));
            }
        } else {
            #pragma unroll
            for (int j = 0; j < 16; j++)
                C[(size_t)(mbase + j) * N + n] = acc[j];
        }
    }
}

// mu/sigma GEMM: grid (128, 2, 2); y = split-K slab index, z = weight select.
// Slab layout in S: [z][by][32][1024]  (4 x 32768 floats)
__global__ void gemm_mu_sigma(const float* __restrict__ A,
                              const float* __restrict__ W0,
                              const float* __restrict__ W1,
                              float* __restrict__ S) {
    const float* W = blockIdx.z ? W1 : W0;
    float* C = S + ((size_t)blockIdx.z * 2 + blockIdx.y) * 32768;
    gemm_body(A, W, C, nullptr, 1024, 1024, 512, 0, blockIdx.x, blockIdx.y);
}

// ffn1 GEMM: grid (512); fused bias+silu epilogue
__global__ void gemm_ffn1(const float* __restrict__ A,
                          const float* __restrict__ W,
                          float* __restrict__ C,
                          const float* __restrict__ bias) {
    gemm_body(A, W, C, bias, 4096, 1024, 1024, 1, blockIdx.x, 0);
}

// ffn2 GEMM: grid (128, 4); split-K plain stores into 4 slabs (no atomics)
__global__ void gemm_ffn2(const float* __restrict__ A,
                          const float* __restrict__ W,
                          float* __restrict__ S) {
    float* C = S + (size_t)blockIdx.y * 32768;
    gemm_body(A, W, C, nullptr, 1024, 4096, 1024, 0, blockIdx.x, blockIdx.y);
}

// ------------- Gaussian-kernel attention row sweep (the big one) ----------
// TWO rows per wave: 16 nt loads (8K+8V) in flight per lane, shuffle-reduce
// only — no LDS, no __syncthreads. Grid 4096 x 256 (4 waves = 8 rows/block).
// mu/sigma arrive as 2 split-K slabs each; combine + bias + tanh here (the
// per-row scalars are wave-uniform, cost is in the noise).
__global__ void attn_kernel(const float* __restrict__ Kp,
                            const float* __restrict__ Vp,
                            const float* __restrict__ Qp,
                            const float* __restrict__ MS,   // mu slabs @0, sg slabs @65536
                            const float* __restrict__ mu_b,
                            const float* __restrict__ sg_b,
                            float* __restrict__ xo) {
    int t = threadIdx.x;
    int lane = t & 63, wid = t >> 6;
    int row0 = blockIdx.x * 8 + wid * 2;
    int row1 = row0 + 1;
    const f32x4* kp0 = (const f32x4*)(Kp + (size_t)row0 * D_DIM);
    const f32x4* vp0 = (const f32x4*)(Vp + (size_t)row0 * D_DIM);
    const f32x4* kp1 = (const f32x4*)(Kp + (size_t)row1 * D_DIM);
    const f32x4* vp1 = (const f32x4*)(Vp + (size_t)row1 * D_DIM);
    f32x4 ka[4], va[4], kb[4], vb[4];
    #pragma unroll
    for (int c = 0; c < 4; c++) ka[c] = __builtin_nontemporal_load(kp0 + c * 64 + lane);
    #pragma unroll
    for (int c = 0; c < 4; c++) kb[c] = __builtin_nontemporal_load(kp1 + c * 64 + lane);
    #pragma unroll
    for (int c = 0; c < 4; c++) va[c] = __builtin_nontemporal_load(vp0 + c * 64 + lane);
    #pragma unroll
    for (int c = 0; c < 4; c++) vb[c] = __builtin_nontemporal_load(vp1 + c * 64 + lane);
    int i0 = row0 & (N_TOK - 1), i1 = row1 & (N_TOK - 1);
    float mu0 = tanhf(MS[row0] + MS[row0 + 32768] + mu_b[i0]);
    float mu1 = tanhf(MS[row1] + MS[row1 + 32768] + mu_b[i1]);
    float sg0 = MS[row0 + 65536] + MS[row0 + 98304] + sg_b[i0];
    float sg1 = MS[row1 + 65536] + MS[row1 + 98304] + sg_b[i1];
    float c0 = -0.5f / (sg0 * sg0 + 1e-8f);
    float c1 = -0.5f / (sg1 * sg1 + 1e-8f);
    float acc0 = 0.f, acc1 = 0.f, d;
    #pragma unroll
    for (int c = 0; c < 4; c++) {
        d = ka[c].x - mu0; acc0 += __expf(c0 * d * d) * va[c].x;
        d = ka[c].y - mu0; acc0 += __expf(c0 * d * d) * va[c].y;
        d = ka[c].z - mu0; acc0 += __expf(c0 * d * d) * va[c].z;
        d = ka[c].w - mu0; acc0 += __expf(c0 * d * d) * va[c].w;
        d = kb[c].x - mu1; acc1 += __expf(c1 * d * d) * vb[c].x;
        d = kb[c].y - mu1; acc1 += __expf(c1 * d * d) * vb[c].y;
        d = kb[c].z - mu1; acc1 += __expf(c1 * d * d) * vb[c].z;
        d = kb[c].w - mu1; acc1 += __expf(c1 * d * d) * vb[c].w;
    }
    acc0 = wave_reduce(acc0);
    acc1 = wave_reduce(acc1);
    if (lane == 0) {
        xo[row0] = acc0 + Qp[row0];
        xo[row1] = acc1 + Qp[row1];
    }
}

// ------------- out = x + (s0+s1+s2+s3) + b2, f32 --------------------------
__global__ void final_kernel(const float* __restrict__ x,
                             const float* __restrict__ F2,  // 4 slabs
                             const float* __restrict__ b2,
                             float* __restrict__ out) {
    int idx = blockIdx.x * 256 + threadIdx.x;    // 32768 total
    float acc = (F2[idx] + F2[idx + 32768]) + (F2[idx + 65536] + F2[idx + 98304]);
    out[idx] = x[idx] + acc + b2[idx & (N_TOK - 1)];
}

extern "C" void kernel_launch(void* const* d_in, const int* in_sizes, int n_in,
                              void* d_out, int out_size, void* d_ws, size_t ws_size,
                              hipStream_t stream) {
    const float* Q       = (const float*)d_in[0];
    const float* Kp      = (const float*)d_in[1];
    const float* Vp      = (const float*)d_in[2];
    const float* mu_w    = (const float*)d_in[3];
    const float* mu_b    = (const float*)d_in[4];
    const float* sigma_w = (const float*)d_in[5];
    const float* sigma_b = (const float*)d_in[6];
    const float* w1      = (const float*)d_in[7];
    const float* b1      = (const float*)d_in[8];
    const float* w2      = (const float*)d_in[9];
    const float* b2      = (const float*)d_in[10];
    const float* ln_ff_g = (const float*)d_in[11];
    const float* ln_ff_b = (const float*)d_in[12];
    const float* ln_q_g  = (const float*)d_in[13];
    const float* ln_q_b  = (const float*)d_in[14];

    // Workspace layout (all fp32). Every buffer is fully overwritten each
    // iteration (plain stores only) -> no memset, no atomics.
    float* ms_sl  = (float*)d_ws;                  // 4 x 32768: mu(by0,by1), sg(by0,by1)
    float* f2_sl  = ms_sl  + 131072;               // 4 x 32768: ffn2 split-K slabs
    float* xbuf   = f2_sl  + 131072;               // 32768
    float* qln    = xbuf   + 32768;                // 32768
    float* h0     = qln    + 32768;                // 32768
    float* g      = h0     + 32768;                // 131072

    // 1) q = LN(Q)
    ln_kernel<<<32, 256, 0, stream>>>(Q, ln_q_g, ln_q_b, qln);

    // 2) mu/sg split-K partials (plain stores into 4 slabs)
    gemm_mu_sigma<<<dim3(128, 2, 2), 256, 0, stream>>>(qln, mu_w, sigma_w, ms_sl);

    // 3) x = sum_d exp(-0.5(K-mu)^2/(sigma^2+1e-8)) * V + Q  (slabs combined here)
    attn_kernel<<<4096, 256, 0, stream>>>(Kp, Vp, Q, ms_sl, mu_b, sigma_b, xbuf);

    // 4) h0 = LN(x)
    ln_kernel<<<32, 256, 0, stream>>>(xbuf, ln_ff_g, ln_ff_b, h0);

    // 5) g = silu(h0 @ w1^T + b1)   (bias+silu fused in epilogue)
    gemm_ffn1<<<512, 256, 0, stream>>>(h0, w1, g, b1);

    // 6) f2 slabs = g @ w2^T partials ; out = x + (sum slabs) + b2
    gemm_ffn2<<<dim3(128, 4), 256, 0, stream>>>(g, w2, f2_sl);
    final_kernel<<<128, 256, 0, stream>>>(xbuf, f2_sl, b2, (float*)d_out);
}